// Round 2
// baseline (991.140 us; speedup 1.0000x reference)
//
#include <hip/hip_runtime.h>
#include <math.h>

#define B_ 16
#define N_ 4096
#define G_ 1024
#define D_ 256
#define DT_ 0.01f
#define EPS_ 1e-5f

__device__ __forceinline__ float fast_tanh(float x) {
    // tanh(x) = 1 - 2/(exp(2x)+1); exact identity, saturates correctly at +-inf
    float e = __expf(2.0f * x);
    return 1.0f - __fdividef(2.0f, e + 1.0f);
}

// ---------------------------------------------------------------------------
// K1: RBF projection  field[b,g,d] = sum_n exp(-(p_n-x_g)^2/(2s^2)) * E[b,n,d]
// Per-batch GEMM M=G(1024) x N=D(256) x K=N(4096), A computed on the fly.
// Tile 128(g) x 128(d), 256 threads, 8x8 micro-tile, K-tile 16.
// ---------------------------------------------------------------------------
__global__ __launch_bounds__(256) void k_proj(const float* __restrict__ emb,
                                              const float* __restrict__ pos,
                                              const float* __restrict__ grd,
                                              const float* __restrict__ sigma_p,
                                              float* __restrict__ field) {
    __shared__ float sX[128];        // grid x values for this g-tile
    __shared__ float sK[16][128];    // kern tile [kk][g_local]
    __shared__ float sE[16][128];    // E tile    [kk][d_local]

    const int t  = threadIdx.x;
    const int bt = blockIdx.z;
    const int g0 = blockIdx.y * 128;
    const int d0 = blockIdx.x * 128;

    const float sg = sigma_p[0];
    const float inv2s2 = 1.0f / (2.0f * sg * sg);

    if (t < 128) sX[t] = grd[(size_t)bt * G_ + g0 + t];
    __syncthreads();

    // kern-compute mapping: thread t fills sK[t>>4][(t&15)*8 .. +7]
    const int kc_kk = t >> 4;
    const int kc_g  = (t & 15) * 8;
    float xv[8];
#pragma unroll
    for (int j = 0; j < 8; ++j) xv[j] = sX[kc_g + j];

    const int tx = t & 15;   // d direction (8 each -> 128)
    const int ty = t >> 4;   // g direction (8 each -> 128)

    float acc[8][8];
#pragma unroll
    for (int i = 0; i < 8; ++i)
#pragma unroll
        for (int j = 0; j < 8; ++j) acc[i][j] = 0.0f;

    const float* Eb = emb + (size_t)bt * N_ * D_;
    const float* Pb = pos + (size_t)bt * N_;

    // E-load mapping: float4 index li in [0,512): kk = li>>5, d-quad = (li&31)*4
    const int li0 = t * 2;
    const int li1 = t * 2 + 1;

    for (int n0 = 0; n0 < N_; n0 += 16) {
        float p = Pb[n0 + kc_kk];
        float kv[8];
#pragma unroll
        for (int j = 0; j < 8; ++j) {
            float dx = p - xv[j];
            kv[j] = __expf(-dx * dx * inv2s2);
        }
        float4 e0 = *(const float4*)&Eb[(size_t)(n0 + (li0 >> 5)) * D_ + d0 + (li0 & 31) * 4];
        float4 e1 = *(const float4*)&Eb[(size_t)(n0 + (li1 >> 5)) * D_ + d0 + (li1 & 31) * 4];
        __syncthreads();
        *(float4*)&sK[kc_kk][kc_g]     = make_float4(kv[0], kv[1], kv[2], kv[3]);
        *(float4*)&sK[kc_kk][kc_g + 4] = make_float4(kv[4], kv[5], kv[6], kv[7]);
        *(float4*)&sE[li0 >> 5][(li0 & 31) * 4] = e0;
        *(float4*)&sE[li1 >> 5][(li1 & 31) * 4] = e1;
        __syncthreads();
#pragma unroll
        for (int kk = 0; kk < 16; ++kk) {
            float a[8], b[8];
            *(float4*)&a[0] = *(const float4*)&sK[kk][ty * 8];
            *(float4*)&a[4] = *(const float4*)&sK[kk][ty * 8 + 4];
            *(float4*)&b[0] = *(const float4*)&sE[kk][tx * 8];
            *(float4*)&b[4] = *(const float4*)&sE[kk][tx * 8 + 4];
#pragma unroll
            for (int i = 0; i < 8; ++i)
#pragma unroll
                for (int j = 0; j < 8; ++j) acc[i][j] += a[i] * b[j];
        }
    }

#pragma unroll
    for (int i = 0; i < 8; ++i) {
        size_t off = ((size_t)bt * G_ + g0 + ty * 8 + i) * D_ + d0 + tx * 8;
        *(float4*)&field[off]     = make_float4(acc[i][0], acc[i][1], acc[i][2], acc[i][3]);
        *(float4*)&field[off + 4] = make_float4(acc[i][4], acc[i][5], acc[i][6], acc[i][7]);
    }
}

// ---------------------------------------------------------------------------
// K2: one diffusion step.
// interference = tanh(field @ W_int + b_int); out = field + DT*(alpha*lap + interference)
// GEMM rows = B*G (16384), cols = 256, K = 256. Tile 128x128, 8x8 micro.
// Laplacian + update fused in epilogue (reads fin neighbors from global).
// ---------------------------------------------------------------------------
__global__ __launch_bounds__(256) void k_diff(const float* __restrict__ fin,
                                              float* __restrict__ fout,
                                              const float* __restrict__ W,
                                              const float* __restrict__ bint,
                                              const float* __restrict__ alpha_p) {
    __shared__ float sA[16][128];    // [kk][row_local]
    __shared__ float sW[16][128];    // [kk][col_local]

    const int t  = threadIdx.x;
    const int r0 = blockIdx.y * 128;
    const int c0 = blockIdx.x * 128;

    const int tx = t & 15;   // col dir
    const int ty = t >> 4;   // row dir

    float acc[8][8];
#pragma unroll
    for (int i = 0; i < 8; ++i)
#pragma unroll
        for (int j = 0; j < 8; ++j) acc[i][j] = 0.0f;

    // A-load mapping: f4 idx li in [0,512): row = li>>2, kq = (li&3)*4
    const int la0 = t * 2, la1 = t * 2 + 1;
    // W-load mapping: f4 idx li in [0,512): kk = li>>5, cq = (li&31)*4
    const int lw0 = t * 2, lw1 = t * 2 + 1;

    for (int k0 = 0; k0 < D_; k0 += 16) {
        float4 a0 = *(const float4*)&fin[(size_t)(r0 + (la0 >> 2)) * D_ + k0 + (la0 & 3) * 4];
        float4 a1 = *(const float4*)&fin[(size_t)(r0 + (la1 >> 2)) * D_ + k0 + (la1 & 3) * 4];
        float4 w0 = *(const float4*)&W[(size_t)(k0 + (lw0 >> 5)) * D_ + c0 + (lw0 & 31) * 4];
        float4 w1 = *(const float4*)&W[(size_t)(k0 + (lw1 >> 5)) * D_ + c0 + (lw1 & 31) * 4];
        __syncthreads();
        {
            int row = la0 >> 2, kq = (la0 & 3) * 4;
            sA[kq + 0][row] = a0.x; sA[kq + 1][row] = a0.y; sA[kq + 2][row] = a0.z; sA[kq + 3][row] = a0.w;
            row = la1 >> 2; kq = (la1 & 3) * 4;
            sA[kq + 0][row] = a1.x; sA[kq + 1][row] = a1.y; sA[kq + 2][row] = a1.z; sA[kq + 3][row] = a1.w;
            *(float4*)&sW[lw0 >> 5][(lw0 & 31) * 4] = w0;
            *(float4*)&sW[lw1 >> 5][(lw1 & 31) * 4] = w1;
        }
        __syncthreads();
#pragma unroll
        for (int kk = 0; kk < 16; ++kk) {
            float a[8], b[8];
            *(float4*)&a[0] = *(const float4*)&sA[kk][ty * 8];
            *(float4*)&a[4] = *(const float4*)&sA[kk][ty * 8 + 4];
            *(float4*)&b[0] = *(const float4*)&sW[kk][tx * 8];
            *(float4*)&b[4] = *(const float4*)&sW[kk][tx * 8 + 4];
#pragma unroll
            for (int i = 0; i < 8; ++i)
#pragma unroll
                for (int j = 0; j < 8; ++j) acc[i][j] += a[i] * b[j];
        }
    }

    const float al = alpha_p[0];
    float bi[8];
    *(float4*)&bi[0] = *(const float4*)&bint[c0 + tx * 8];
    *(float4*)&bi[4] = *(const float4*)&bint[c0 + tx * 8 + 4];

#pragma unroll
    for (int i = 0; i < 8; ++i) {
        int r = r0 + ty * 8 + i;
        int g = r & (G_ - 1);
        const float* rc = fin + (size_t)r * D_ + c0 + tx * 8;
        const float* ru = fin + (size_t)(g == 0 ? r : r - 1) * D_ + c0 + tx * 8;
        const float* rd = fin + (size_t)(g == G_ - 1 ? r : r + 1) * D_ + c0 + tx * 8;
        float fc[8], fu[8], fd[8];
        *(float4*)&fc[0] = *(const float4*)&rc[0]; *(float4*)&fc[4] = *(const float4*)&rc[4];
        *(float4*)&fu[0] = *(const float4*)&ru[0]; *(float4*)&fu[4] = *(const float4*)&ru[4];
        *(float4*)&fd[0] = *(const float4*)&rd[0]; *(float4*)&fd[4] = *(const float4*)&rd[4];
        float o[8];
#pragma unroll
        for (int j = 0; j < 8; ++j) {
            float y   = fast_tanh(acc[i][j] + bi[j]);
            float lap = fu[j] + fd[j] - 2.0f * fc[j];
            o[j] = fc[j] + DT_ * (al * lap + y);
        }
        float* po = fout + (size_t)r * D_ + c0 + tx * 8;
        *(float4*)&po[0] = make_float4(o[0], o[1], o[2], o[3]);
        *(float4*)&po[4] = make_float4(o[4], o[5], o[6], o[7]);
    }
}

// ---------------------------------------------------------------------------
// K3: sample field at token positions + residual + LayerNorm1.
// One wave per row (D=256 -> 4 floats/lane). enhanced -> d_out (K4 in-place).
// ---------------------------------------------------------------------------
__global__ __launch_bounds__(256) void k_sample(const float* __restrict__ field,
                                                const float* __restrict__ emb,
                                                const float* __restrict__ pos,
                                                const float* __restrict__ g1,
                                                const float* __restrict__ b1,
                                                float* __restrict__ enh) {
    const int row  = blockIdx.x * 4 + (threadIdx.x >> 6);
    const int lane = threadIdx.x & 63;
    const int b    = row >> 12;            // row / N
    const int d    = lane * 4;

    float p  = pos[row];
    float u  = p * (float)(G_ - 1);
    float fi = floorf(u);
    fi = fminf(fmaxf(fi, 0.0f), (float)(G_ - 2));
    int   i0 = (int)fi;
    float w  = u - fi;

    const float4 f0v = *(const float4*)&field[((size_t)(b << 10) + i0) * D_ + d];
    const float4 f1v = *(const float4*)&field[((size_t)(b << 10) + i0 + 1) * D_ + d];
    const float4 ev  = *(const float4*)&emb[(size_t)row * D_ + d];

    float y[4];
    y[0] = f0v.x + w * (f1v.x - f0v.x) + ev.x;
    y[1] = f0v.y + w * (f1v.y - f0v.y) + ev.y;
    y[2] = f0v.z + w * (f1v.z - f0v.z) + ev.z;
    y[3] = f0v.w + w * (f1v.w - f0v.w) + ev.w;

    float s1 = y[0] + y[1] + y[2] + y[3];
    float s2 = y[0]*y[0] + y[1]*y[1] + y[2]*y[2] + y[3]*y[3];
#pragma unroll
    for (int m = 1; m < 64; m <<= 1) {
        s1 += __shfl_xor(s1, m);
        s2 += __shfl_xor(s2, m);
    }
    float mu  = s1 * (1.0f / 256.0f);
    float var = s2 * (1.0f / 256.0f) - mu * mu;
    float rs  = rsqrtf(var + EPS_);

    const float4 gv = *(const float4*)&g1[d];
    const float4 bv = *(const float4*)&b1[d];
    float4 o;
    o.x = (y[0] - mu) * rs * gv.x + bv.x;
    o.y = (y[1] - mu) * rs * gv.y + bv.y;
    o.z = (y[2] - mu) * rs * gv.z + bv.z;
    o.w = (y[3] - mu) * rs * gv.w + bv.w;
    *(float4*)&enh[(size_t)row * D_ + d] = o;
}

// ---------------------------------------------------------------------------
// K4: out = LN2(enhanced @ W_out + b_out + enhanced). In-place on d_out.
// Block: 64 rows x 256 cols (full width so LN2 fuses). 256 thr, 8x8 micro.
// Thread map: tx = t&31 (col, 8 each), ty = t>>5 (8 rows each).
// ---------------------------------------------------------------------------
__global__ __launch_bounds__(256) void k_out(const float* __restrict__ enh,
                                             const float* __restrict__ W,
                                             const float* __restrict__ bo,
                                             const float* __restrict__ g2,
                                             const float* __restrict__ b2,
                                             float* __restrict__ out) {
    __shared__ float sA[16][64];     // [kk][row]
    __shared__ float sW[16][256];    // [kk][col]

    const int t  = threadIdx.x;
    const int r0 = blockIdx.x * 64;
    const int tx = t & 31;
    const int ty = t >> 5;

    float acc[8][8];
#pragma unroll
    for (int i = 0; i < 8; ++i)
#pragma unroll
        for (int j = 0; j < 8; ++j) acc[i][j] = 0.0f;

    const int arow = t >> 2, akq = (t & 3) * 4;   // A-load: 1 f4/thread

    for (int k0 = 0; k0 < D_; k0 += 16) {
        float4 av = *(const float4*)&enh[(size_t)(r0 + arow) * D_ + k0 + akq];
        float4 wv[4];
#pragma unroll
        for (int q = 0; q < 4; ++q) {
            int li = t + 256 * q;                  // kk = li>>6, cq = (li&63)*4
            wv[q] = *(const float4*)&W[(size_t)(k0 + (li >> 6)) * D_ + (li & 63) * 4];
        }
        __syncthreads();
        sA[akq + 0][arow] = av.x; sA[akq + 1][arow] = av.y;
        sA[akq + 2][arow] = av.z; sA[akq + 3][arow] = av.w;
#pragma unroll
        for (int q = 0; q < 4; ++q) {
            int li = t + 256 * q;
            *(float4*)&sW[li >> 6][(li & 63) * 4] = wv[q];
        }
        __syncthreads();
#pragma unroll
        for (int kk = 0; kk < 16; ++kk) {
            float a[8], b[8];
            *(float4*)&a[0] = *(const float4*)&sA[kk][ty * 8];
            *(float4*)&a[4] = *(const float4*)&sA[kk][ty * 8 + 4];
            *(float4*)&b[0] = *(const float4*)&sW[kk][tx * 8];
            *(float4*)&b[4] = *(const float4*)&sW[kk][tx * 8 + 4];
#pragma unroll
            for (int i = 0; i < 8; ++i)
#pragma unroll
                for (int j = 0; j < 8; ++j) acc[i][j] += a[i] * b[j];
        }
    }

    const int c = tx * 8;
    float bov[8], g2v[8], b2v[8];
    *(float4*)&bov[0] = *(const float4*)&bo[c];  *(float4*)&bov[4] = *(const float4*)&bo[c + 4];
    *(float4*)&g2v[0] = *(const float4*)&g2[c];  *(float4*)&g2v[4] = *(const float4*)&g2[c + 4];
    *(float4*)&b2v[0] = *(const float4*)&b2[c];  *(float4*)&b2v[4] = *(const float4*)&b2[c + 4];

#pragma unroll
    for (int i = 0; i < 8; ++i) {
        int r = r0 + ty * 8 + i;
        float e[8];
        const float* pe = enh + (size_t)r * D_ + c;
        *(float4*)&e[0] = *(const float4*)&pe[0];
        *(float4*)&e[4] = *(const float4*)&pe[4];
        float y[8];
        float s1 = 0.0f, s2 = 0.0f;
#pragma unroll
        for (int j = 0; j < 8; ++j) {
            y[j] = acc[i][j] + bov[j] + e[j];
            s1 += y[j];
            s2 += y[j] * y[j];
        }
        // reduce across the 32 tx lanes (they occupy one 32-lane half of the wave)
#pragma unroll
        for (int m = 1; m < 32; m <<= 1) {
            s1 += __shfl_xor(s1, m);
            s2 += __shfl_xor(s2, m);
        }
        float mu  = s1 * (1.0f / 256.0f);
        float var = s2 * (1.0f / 256.0f) - mu * mu;
        float rs  = rsqrtf(var + EPS_);
        float o[8];
#pragma unroll
        for (int j = 0; j < 8; ++j) o[j] = (y[j] - mu) * rs * g2v[j] + b2v[j];
        float* po = out + (size_t)r * D_ + c;
        *(float4*)&po[0] = make_float4(o[0], o[1], o[2], o[3]);
        *(float4*)&po[4] = make_float4(o[4], o[5], o[6], o[7]);
    }
}

// ---------------------------------------------------------------------------
extern "C" void kernel_launch(void* const* d_in, const int* in_sizes, int n_in,
                              void* d_out, int out_size, void* d_ws, size_t ws_size,
                              hipStream_t stream) {
    const float* emb   = (const float*)d_in[0];
    const float* pos   = (const float*)d_in[1];
    const float* grd   = (const float*)d_in[2];
    const float* sigma = (const float*)d_in[3];
    const float* alpha = (const float*)d_in[4];
    const float* W_int = (const float*)d_in[5];
    const float* b_int = (const float*)d_in[6];
    const float* W_out = (const float*)d_in[7];
    const float* b_out = (const float*)d_in[8];
    const float* g1    = (const float*)d_in[9];
    const float* b1    = (const float*)d_in[10];
    const float* g2    = (const float*)d_in[11];
    const float* b2    = (const float*)d_in[12];
    float* out = (float*)d_out;

    float* f0 = (float*)d_ws;
    float* f1 = f0 + (size_t)B_ * G_ * D_;

    // 1) projection
    k_proj<<<dim3(D_ / 128, G_ / 128, B_), 256, 0, stream>>>(emb, pos, grd, sigma, f0);
    // 2) 4 diffusion steps (ping-pong f0 <-> f1, ends in f0)
    k_diff<<<dim3(D_ / 128, (B_ * G_) / 128), 256, 0, stream>>>(f0, f1, W_int, b_int, alpha);
    k_diff<<<dim3(D_ / 128, (B_ * G_) / 128), 256, 0, stream>>>(f1, f0, W_int, b_int, alpha);
    k_diff<<<dim3(D_ / 128, (B_ * G_) / 128), 256, 0, stream>>>(f0, f1, W_int, b_int, alpha);
    k_diff<<<dim3(D_ / 128, (B_ * G_) / 128), 256, 0, stream>>>(f1, f0, W_int, b_int, alpha);
    // 3) sample + residual + LN1 -> d_out (used as 'enhanced')
    k_sample<<<(B_ * N_) / 4, 256, 0, stream>>>(f0, emb, pos, g1, b1, out);
    // 4) out-proj + residual + LN2, in-place on d_out
    k_out<<<(B_ * N_) / 64, 256, 0, stream>>>(out, W_out, b_out, g2, b2, out);
}